// Round 5
// baseline (121.155 us; speedup 1.0000x reference)
//
#include <hip/hip_runtime.h>
#include <hip/hip_bf16.h>

// Shift SSM == causal 64-tap FIR per channel + skip (D folded into tap 0).
// R5: MFMA formulation (as R4) with ALL per-h work hoisted into a tiny
// pre-kernel: taps K[h][k] AND the pre-packed per-lane MFMA b-fragments
// F[h][c][lane] go to d_ws. Main kernel: 3 frag loads + u->LDS bf16 staging
// + ONE barrier + 12 mfma_f32_16x16x32_bf16 + stores. HBM-bound target.

#define D_MODEL 512
#define D_STATE 64
#define BATCH   8
#define SEQ_L   4096
#define NT      256

typedef short           s16x8 __attribute__((ext_vector_type(8)));
typedef unsigned short  u16;
typedef u16             u16x4 __attribute__((ext_vector_type(4)));
typedef u16             u16x8 __attribute__((ext_vector_type(8)));
typedef float           f32x4 __attribute__((ext_vector_type(4)));

#define K_BYTES    (D_MODEL * D_STATE * 4)            // 128 KB fp32 taps
#define FRAG_BYTES (D_MODEL * 3 * 64 * 16)            // 1.5 MB packed b-frags

// XOR swizzle on 16B LDS chunks (write AND read sides).
__device__ __forceinline__ int SW(int g) { return g ^ ((g >> 3) & 7); }

__device__ __forceinline__ u16 f2bf(float f) {        // RNE float -> bf16
    unsigned v = __builtin_bit_cast(unsigned, f);
    return (u16)((v + 0x7FFFu + ((v >> 16) & 1u)) >> 16);
}

// ---- pre-kernel: one wave per h. K[h][k] fp32 + packed b-frags. ----
__global__ void __launch_bounds__(64)
taps_kernel(const float* __restrict__ B, const float* __restrict__ C,
            const float* __restrict__ D, float* __restrict__ Kws,
            u16x8* __restrict__ F, int do_frags) {
    const int h = blockIdx.x;
    const int t = threadIdx.x;               // 0..63
    __shared__ float Bs[D_STATE];
    __shared__ float Cs[2 * D_STATE];        // zero-padded tail
    __shared__ float Kf[D_STATE];

    if (t < 16) {
        ((float4*)Bs)[t] = ((const float4*)(B + h * D_STATE))[t];
    } else if (t < 48) {
        const int j = t - 16;
        ((float4*)Cs)[j] = (j < 16) ? ((const float4*)(C + h * D_STATE))[j]
                                    : make_float4(0.f, 0.f, 0.f, 0.f);
    }
    __syncthreads();

    float s = 0.f;
    #pragma unroll
    for (int j = 0; j < D_STATE; ++j) s = fmaf(Bs[j], Cs[t + j], s);
    if (t == 0) s += D[h];
    Kws[h * D_STATE + t] = s;
    Kf[t] = s;
    __syncthreads();

    if (do_frags) {
        const int n = t & 15, q = t >> 4;
        #pragma unroll
        for (int c = 0; c < 3; ++c) {
            u16x8 fr;
            #pragma unroll
            for (int j = 0; j < 8; ++j) {
                const int k = 64 + n - (32 * c + 8 * q + j);
                fr[j] = (k >= 0 && k < D_STATE) ? f2bf(Kf[k]) : (u16)0;
            }
            F[(h * 3 + c) * 64 + t] = fr;
        }
    }
}

// ---- main kernel: one block per (b,h) row ----
template <bool FRAGS>
__global__ void __launch_bounds__(NT)
shift_mfma(const float* __restrict__ u, const float* __restrict__ Kws,
           const u16x8* __restrict__ F, float* __restrict__ y) {
    const int row = blockIdx.x;              // b*512 + h
    const int h   = row & (D_MODEL - 1);
    const float* __restrict__ urow = u + (size_t)row * SEQ_L;
    float* __restrict__ yrow       = y + (size_t)row * SEQ_L;

    __shared__ u16 ub[536 * 8];              // bf16 row, 64-elem halo + tail

    const int t = threadIdx.x;
    const int l = t & 63, n = l & 15, q = l >> 4;

    // b-frags: issue global loads first (L2-broadcast across 8 batch rows)
    s16x8 bfr[3];
    if (FRAGS) {
        #pragma unroll
        for (int c = 0; c < 3; ++c)
            bfr[c] = __builtin_bit_cast(s16x8, F[(h * 3 + c) * 64 + l]);
    }

    // stage u row -> bf16 LDS (coalesced float4 reads, swizzled b64 writes)
    float4 v[4];
    #pragma unroll
    for (int j = 0; j < 4; ++j)
        v[j] = *(const float4*)(urow + 4 * t + 1024 * j);

    if (t < 8) {                             // front halo (elems 0..63)
        u16x8 z = {0,0,0,0,0,0,0,0};
        *(u16x8*)((char*)ub + (SW(t) << 4)) = z;
    } else if (t < 20) {                     // tail pad (chunks 520..531)
        u16x8 z = {0,0,0,0,0,0,0,0};
        *(u16x8*)((char*)ub + (SW(520 + t - 8) << 4)) = z;
    }
    #pragma unroll
    for (int j = 0; j < 4; ++j) {
        u16x4 pk = { f2bf(v[j].x), f2bf(v[j].y), f2bf(v[j].z), f2bf(v[j].w) };
        const int byte = 128 + 8 * t + 2048 * j;          // 128B front halo
        const int sb   = (SW(byte >> 4) << 4) | (byte & 8);
        *(u16x4*)((char*)ub + sb) = pk;
    }

    if (!FRAGS) {                            // fallback: build frags from K
        const float* Kg = Kws + h * D_STATE;
        #pragma unroll
        for (int c = 0; c < 3; ++c)
            #pragma unroll
            for (int j = 0; j < 8; ++j) {
                const int k = 64 + n - (32 * c + 8 * q + j);
                bfr[c][j] = (short)((k >= 0 && k < D_STATE) ? f2bf(Kg[k]) : (u16)0);
            }
    }
    __syncthreads();

    // 4 tiles of 256 outputs per wave
    const int wbase = 1024 * (t >> 6);
    #pragma unroll
    for (int tt = 0; tt < 4; ++tt) {
        const int base = wbase + 256 * tt;
        f32x4 acc = {0.f, 0.f, 0.f, 0.f};
        #pragma unroll
        for (int c = 0; c < 3; ++c) {
            // A[m][p]: lane m=n reads 8 bf16 at L = base + 16n + 32c + 8q
            const int L  = base + 16 * n + 32 * c + 8 * q;
            const int sb = SW(L >> 3) << 4;
            const s16x8 a = *(const s16x8*)((const char*)ub + sb);
            acc = __builtin_amdgcn_mfma_f32_16x16x32_bf16(a, bfr[c], acc, 0, 0, 0);
        }
        #pragma unroll
        for (int r = 0; r < 4; ++r)
            yrow[base + 16 * (4 * q + r) + n] = acc[r];
    }
}

extern "C" void kernel_launch(void* const* d_in, const int* in_sizes, int n_in,
                              void* d_out, int out_size, void* d_ws, size_t ws_size,
                              hipStream_t stream) {
    const float* u = (const float*)d_in[0];   // (8, 512, 4096)
    const float* B = (const float*)d_in[1];   // (512, 64)
    const float* C = (const float*)d_in[2];   // (1, 512, 64)
    const float* D = (const float*)d_in[3];   // (512,)
    float* y = (float*)d_out;                 // (8, 512, 4096)

    float* Kws = (float*)d_ws;
    u16x8* F   = (u16x8*)((char*)d_ws + K_BYTES);
    const bool frags = ws_size >= (size_t)(K_BYTES + FRAG_BYTES);

    taps_kernel<<<dim3(D_MODEL), dim3(64), 0, stream>>>(B, C, D, Kws, F,
                                                        frags ? 1 : 0);
    if (frags)
        shift_mfma<true><<<dim3(BATCH * D_MODEL), dim3(NT), 0, stream>>>(u, Kws, F, y);
    else
        shift_mfma<false><<<dim3(BATCH * D_MODEL), dim3(NT), 0, stream>>>(u, Kws, F, y);
}